// Round 14
// baseline (201.024 us; speedup 1.0000x reference)
//
#include <hip/hip_runtime.h>
#include <math.h>

#define B_ 8
#define T_ 2048
#define D_ 1024
#define H_ 128
#define BT (B_ * T_)

typedef short bf16x8 __attribute__((ext_vector_type(8)));
typedef float f32x4 __attribute__((ext_vector_type(4)));

static constexpr float SCALE2 = 0.127517416f;  // (1/sqrt(128)) * log2(e)

__device__ inline unsigned short f2b(float f) {
  unsigned int u = __float_as_uint(f);
  u += 0x7FFF + ((u >> 16) & 1);  // RNE
  return (unsigned short)(u >> 16);
}
__device__ inline unsigned int pk2(float a, float b) {
  return (unsigned int)f2b(a) | ((unsigned int)f2b(b) << 16);
}
__device__ inline float b2f(unsigned short u) {
  return __uint_as_float((unsigned int)u << 16);
}

// global (AS1) -> LDS (AS3) direct 16B copy; dest = wave-uniform base + lane*16
__device__ __forceinline__ void gll16(const void* g, void* l) {
  __builtin_amdgcn_global_load_lds(
      (const __attribute__((address_space(1))) void*)g,
      (__attribute__((address_space(3))) void*)l, 16, 0, 0);
}

// ---------------------------------------------------------------------------
// Setup: W[d][h] fp32 -> Wt[sel][h][d] bf16 through LDS, coalesced stores.
// ---------------------------------------------------------------------------
__global__ __launch_bounds__(256) void wcvt_kernel(
    const float* __restrict__ Wq, const float* __restrict__ Wk,
    const float* __restrict__ Wv, short* __restrict__ Wt) {
  __shared__ short Wls[128 * 72];  // [h][d] bf16, pitch 72
  const int sel = blockIdx.y;
  const float* W = sel == 0 ? Wq : (sel == 1 ? Wk : Wv);
  const int d0 = blockIdx.x * 64;
  const int tid = threadIdx.x;
#pragma unroll
  for (int i = 0; i < 8; ++i) {
    int slot = tid + i * 256;         // 2048 float4 slots: 64 d x 32 h-groups
    int r = slot >> 5, hg = slot & 31;
    float4 w = *(const float4*)(W + (size_t)(d0 + r) * H_ + hg * 4);
    Wls[(hg * 4 + 0) * 72 + r] = (short)f2b(w.x);
    Wls[(hg * 4 + 1) * 72 + r] = (short)f2b(w.y);
    Wls[(hg * 4 + 2) * 72 + r] = (short)f2b(w.z);
    Wls[(hg * 4 + 3) * 72 + r] = (short)f2b(w.w);
  }
  __syncthreads();
  short* dst = Wt + (size_t)sel * D_ * H_;
#pragma unroll
  for (int i = 0; i < 4; ++i) {
    int slot = tid + i * 256;         // 1024 int4 slots: 128 h x 8 d-groups
    int h = slot >> 3, g = slot & 7;
    *(int4*)(dst + (size_t)h * D_ + d0 + g * 8) = *(int4*)&Wls[h * 72 + g * 8];
  }
}

// ---------------------------------------------------------------------------
// Proj: unchanged (issue-early/pack-late X, gll W, dbuf, 64x128 tile).
// ---------------------------------------------------------------------------
__global__ __launch_bounds__(256) void proj_kernel(
    const float* __restrict__ x, const short* __restrict__ Wt,
    short* __restrict__ qb, short* __restrict__ kb, short* __restrict__ vtb) {
  __shared__ alignas(16) char smem[49152];
  short* Xs0 = (short*)smem;             // [64][64] bf16 swizzled
  short* Xs1 = (short*)(smem + 8192);
  short* Ws0 = (short*)(smem + 16384);   // [128][64] bf16 swizzled
  short* Ws1 = (short*)(smem + 32768);

  const int tid = threadIdx.x;
  const int wave = tid >> 6, lane = tid & 63;
  const int ln = lane & 15, quad = lane >> 4;
  const int mw = wave & 1, nw = wave >> 1;  // wave tile: 32 rows x 64 cols
  const int sel = blockIdx.y;
  const int row0 = blockIdx.x * 64;
  const short* W = Wt + (size_t)sel * (size_t)(D_ * H_);

  f32x4 acc[2][4];
#pragma unroll
  for (int mi = 0; mi < 2; ++mi)
#pragma unroll
    for (int ni = 0; ni < 4; ++ni) acc[mi][ni] = (f32x4){0.f, 0.f, 0.f, 0.f};

  auto stageW = [&](int bf, int k0) {
    short* Ws = bf ? Ws1 : Ws0;
#pragma unroll
    for (int j = 0; j < 4; ++j) {
      const int rbase = wave * 32 + j * 8;
      const int n = rbase + (lane >> 3);
      const int gp = (lane & 7) ^ (n & 7);
      gll16(W + (size_t)n * D_ + k0 + gp * 8, (char*)Ws + rbase * 128);
    }
  };
  auto packX = [&](int bf, const float4* xr) {
    short* Xs = bf ? Xs1 : Xs0;
#pragma unroll
    for (int i = 0; i < 4; ++i) {
      int fid = tid + i * 256;
      int r = fid >> 4, g4 = fid & 15;
      int g = g4 >> 1, half = g4 & 1;
      unsigned int* p = (unsigned int*)&Xs[r * 64 + ((g ^ (r & 7)) * 8) + half * 4];
      p[0] = pk2(xr[i].x, xr[i].y);
      p[1] = pk2(xr[i].z, xr[i].w);
    }
  };

  {  // prologue: stage 0
    stageW(0, 0);
    float4 xr[4];
#pragma unroll
    for (int i = 0; i < 4; ++i) {
      int fid = tid + i * 256;
      int r = fid >> 4, g4 = fid & 15;
      xr[i] = *(const float4*)(x + (size_t)(row0 + r) * D_ + g4 * 4);
    }
    packX(0, xr);
  }

  for (int s = 0; s < 16; ++s) {
    __syncthreads();  // drains gll W(s) + pack(s) ds_writes
    float4 xr[4];
    const bool pre = (s < 15);
    if (pre) {
      const int k0n = (s + 1) * 64;
      stageW((s + 1) & 1, k0n);
#pragma unroll
      for (int i = 0; i < 4; ++i) {   // issue early...
        int fid = tid + i * 256;
        int r = fid >> 4, g4 = fid & 15;
        xr[i] = *(const float4*)(x + (size_t)(row0 + r) * D_ + k0n + g4 * 4);
      }
    }
    const short* Xs = (s & 1) ? Xs1 : Xs0;
    const short* Ws = (s & 1) ? Ws1 : Ws0;
#pragma unroll
    for (int kk = 0; kk < 2; ++kk) {
      bf16x8 a[2];
#pragma unroll
      for (int mi = 0; mi < 2; ++mi) {
        int r = mw * 32 + mi * 16 + ln;
        a[mi] = *(bf16x8*)&Xs[r * 64 + (((kk * 4 + quad) ^ (r & 7)) * 8)];
      }
#pragma unroll
      for (int ni = 0; ni < 4; ++ni) {
        int n = nw * 64 + ni * 16 + ln;
        bf16x8 bb = *(bf16x8*)&Ws[n * 64 + (((kk * 4 + quad) ^ (n & 7)) * 8)];
#pragma unroll
        for (int mi = 0; mi < 2; ++mi)
          acc[mi][ni] = __builtin_amdgcn_mfma_f32_16x16x32_bf16(a[mi], bb, acc[mi][ni], 0, 0, 0);
      }
    }
    if (pre) packX((s + 1) & 1, xr);  // ...use late (after compute)
  }

  __syncthreads();  // tiles dead; reuse smem for epilogue repack
  short* Cs = (short*)smem;
  if (sel < 2) {
    short* out = sel ? kb : qb;
#pragma unroll
    for (int mi = 0; mi < 2; ++mi)
#pragma unroll
      for (int ni = 0; ni < 4; ++ni)
#pragma unroll
        for (int rr = 0; rr < 4; ++rr)
          Cs[(mw * 32 + mi * 16 + quad * 4 + rr) * 136 + nw * 64 + ni * 16 + ln] =
              (short)f2b(acc[mi][ni][rr]);
    __syncthreads();
#pragma unroll
    for (int i = 0; i < 4; ++i) {
      int slot = tid + i * 256;          // 1024 int4 slots: 64 rows x 16
      int r = slot >> 4, g = slot & 15;
      *(int4*)(out + (size_t)(row0 + r) * H_ + g * 8) = *(int4*)&Cs[r * 136 + g * 8];
    }
  } else {
#pragma unroll
    for (int mi = 0; mi < 2; ++mi)
#pragma unroll
      for (int ni = 0; ni < 4; ++ni)
#pragma unroll
        for (int rr = 0; rr < 4; ++rr)
          Cs[(nw * 64 + ni * 16 + ln) * 72 + mw * 32 + mi * 16 + quad * 4 + rr] =
              (short)f2b(acc[mi][ni][rr]);
    __syncthreads();
    const int b = row0 >> 11, t0 = row0 & 2047;
#pragma unroll
    for (int i = 0; i < 4; ++i) {
      int slot = tid + i * 256;          // 1024 int4 slots: 128 h x 8
      int h = slot >> 3, g = slot & 7;
      *(int4*)(vtb + (size_t)(b * H_ + h) * T_ + t0 + g * 8) = *(int4*)&Cs[h * 72 + g * 8];
    }
  }
}

// ---------------------------------------------------------------------------
// Attention part 1 v4: WAVE-AUTONOMOUS, ZERO BARRIERS. One wave (64 thr) per
// (16q-tile, key-segment<=8 chunks) task; K/V fragments loaded directly from
// global (L2) into registers -- no staging LDS, no __syncthreads anywhere.
// P's C->B transform via wave-private LDS (lgkm-ordered). Grid = task*8 + b
// so batch b pins to XCD b (blockIdx%8): each XCD's L2 caches its batch's
// ~1.5 MB K/V/Q working set. 2560 blocks, heavy segments first.
// ---------------------------------------------------------------------------
__global__ __launch_bounds__(64, 3) void attn_part(
    const short* __restrict__ qb, const short* __restrict__ kb,
    const short* __restrict__ vtb, short* __restrict__ po,
    float* __restrict__ pm, float* __restrict__ pl) {
  __shared__ short myP[16 * 68];  // one wave per block: wave-private

  const int lane = threadIdx.x;
  const int ln = lane & 15, quad = lane >> 4;
  const int b = blockIdx.x & 7;              // batch -> XCD pin
  const int task = 319 - (blockIdx.x >> 3);  // heavy-first
  // decode task -> (a, ti, s); a-group has 4 tiles x nseg segments
  int a, base, nseg;
  if (task < 32)       { a = task >> 2;              base = 4 * a;             nseg = 1; }
  else if (task < 96)  { a = 8 + ((task - 32) >> 3); base = 32 + 8 * (a - 8);  nseg = 2; }
  else if (task < 192) { a = 16 + (task - 96) / 12;  base = 96 + 12 * (a - 16); nseg = 3; }
  else                 { a = 24 + ((task - 192) >> 4); base = 192 + 16 * (a - 24); nseg = 4; }
  const int local = task - base;
  const int ti = local / nseg;
  const int s = local - ti * nseg;
  const int j2 = 4 * a + ti;          // 16q tile index within batch
  const int q0 = j2 * 16;
  const int c = a + 1;                // chunks for this tile
  const int ch0 = 8 * s, ch1 = min(8 * s + 8, c);
  const int sid = b * 320 + task;     // partial storage slot

  bf16x8 qfr[4];  // this wave's 16 queries, B-operand layout
#pragma unroll
  for (int kk = 0; kk < 4; ++kk)
    qfr[kk] = *(const bf16x8*)(qb + (size_t)(b * T_ + q0 + ln) * H_ +
                               kk * 32 + quad * 8);

  f32x4 oacc[8];  // O^T: h = ht*16+quad*4+r, q = ln
#pragma unroll
  for (int ht = 0; ht < 8; ++ht) oacc[ht] = (f32x4){0.f, 0.f, 0.f, 0.f};

  float m_run = -INFINITY, l_run = 0.f;
  const int qg = q0 + ln;

  const short* kbase = kb + (size_t)b * T_ * H_;
  const short* vbase = vtb + (size_t)b * H_ * T_;

  for (int ch = ch0; ch < ch1; ++ch) {
    const int s0 = ch * 64;

    // S^T = K * Q^T : 16 K frags straight from global (L2), 16 MFMAs
    f32x4 sacc[4];
#pragma unroll
    for (int t = 0; t < 4; ++t) sacc[t] = (f32x4){0.f, 0.f, 0.f, 0.f};
#pragma unroll
    for (int kk = 0; kk < 4; ++kk) {
#pragma unroll
      for (int t = 0; t < 4; ++t) {
        bf16x8 kf = *(const bf16x8*)(kbase + (size_t)(s0 + t * 16 + ln) * H_ +
                                     kk * 32 + quad * 8);
        sacc[t] = __builtin_amdgcn_mfma_f32_16x16x32_bf16(kf, qfr[kk], sacc[t], 0, 0, 0);
      }
    }

    // wave-local online softmax (log2 domain)
    const bool needMask = (s0 + 63 > q0);
    float sv[4][4];
    float mc = -INFINITY;
#pragma unroll
    for (int t = 0; t < 4; ++t)
#pragma unroll
      for (int r = 0; r < 4; ++r) {
        float scv = sacc[t][r] * SCALE2;
        if (needMask) {
          const int key = s0 + t * 16 + quad * 4 + r;
          scv = (key <= qg) ? scv : -INFINITY;
        }
        sv[t][r] = scv;
        mc = fmaxf(mc, scv);
      }
    mc = fmaxf(mc, __shfl_xor(mc, 16));
    mc = fmaxf(mc, __shfl_xor(mc, 32));
    const float mnew = fmaxf(m_run, mc);
    const float alpha = exp2f(m_run - mnew);
    float lc = 0.f;
    float p[4][4];
#pragma unroll
    for (int t = 0; t < 4; ++t)
#pragma unroll
      for (int r = 0; r < 4; ++r) {
        p[t][r] = exp2f(sv[t][r] - mnew);
        lc += p[t][r];
      }
    lc += __shfl_xor(lc, 16);
    lc += __shfl_xor(lc, 32);
    l_run = l_run * alpha + lc;
    m_run = mnew;

    // P^T -> wave-private LDS (lgkm-ordered, no barrier)
#pragma unroll
    for (int t = 0; t < 4; ++t) {
      *(unsigned int*)&myP[ln * 68 + t * 16 + quad * 4 + 0] = pk2(p[t][0], p[t][1]);
      *(unsigned int*)&myP[ln * 68 + t * 16 + quad * 4 + 2] = pk2(p[t][2], p[t][3]);
    }
#pragma unroll
    for (int ht = 0; ht < 8; ++ht)
#pragma unroll
      for (int r = 0; r < 4; ++r) oacc[ht][r] *= alpha;

    // O^T += V^T * P^T : 16 V frags straight from global (L2), 16 MFMAs
#pragma unroll
    for (int kk2 = 0; kk2 < 2; ++kk2) {
      bf16x8 pf = *(bf16x8*)&myP[ln * 68 + kk2 * 32 + quad * 8];
#pragma unroll
      for (int ht = 0; ht < 8; ++ht) {
        bf16x8 vf = *(const bf16x8*)(vbase + (size_t)(ht * 16 + ln) * T_ +
                                     s0 + kk2 * 32 + quad * 8);
        oacc[ht] = __builtin_amdgcn_mfma_f32_16x16x32_bf16(vf, pf, oacc[ht], 0, 0, 0);
      }
    }
  }

  // partial write: m, l (quad 0), un-normalized O as bf16, direct from frags
  if (quad == 0) {
    pm[(size_t)sid * 16 + ln] = m_run;
    pl[(size_t)sid * 16 + ln] = l_run;
  }
  short* dst = po + (size_t)sid * 2048;  // [16 q][128 h] bf16
#pragma unroll
  for (int ht = 0; ht < 8; ++ht) {
    int2 w2;
    w2.x = (int)pk2(oacc[ht][0], oacc[ht][1]);
    w2.y = (int)pk2(oacc[ht][2], oacc[ht][3]);
    *(int2*)(dst + ln * 128 + ht * 16 + quad * 4) = w2;
  }
}

// ---------------------------------------------------------------------------
// Attention part 2: combine <=4 bf16 partials per 16q tile (log2-domain
// rescale). 1024 blocks x 256 thr (16 q x 16 h-groups of 8).
// ---------------------------------------------------------------------------
__global__ __launch_bounds__(256) void attn_reduce(
    const short* __restrict__ po, const float* __restrict__ pm,
    const float* __restrict__ pl, float* __restrict__ out) {
  const int b = blockIdx.x >> 7;
  const int j2 = blockIdx.x & 127;
  const int a = j2 >> 2;
  const int nseg = (a >> 3) + 1;
  const int base = (a < 8) ? 4 * a
                 : (a < 16) ? 32 + 8 * (a - 8)
                 : (a < 24) ? 96 + 12 * (a - 16)
                 : 192 + 16 * (a - 24);
  const int sid0 = b * 320 + base + (j2 & 3) * nseg;
  const int tid = threadIdx.x;
  const int q = tid >> 4, h0 = (tid & 15) * 8;

  float m2[4], l[4], w[4];
  float M2 = -INFINITY;
  for (int s2 = 0; s2 < nseg; ++s2) {
    m2[s2] = pm[(size_t)(sid0 + s2) * 16 + q];
    l[s2] = pl[(size_t)(sid0 + s2) * 16 + q];
    M2 = fmaxf(M2, m2[s2]);
  }
  float lsum = 0.f;
  for (int s2 = 0; s2 < nseg; ++s2) {
    w[s2] = exp2f(m2[s2] - M2);
    lsum += w[s2] * l[s2];
  }
  float acc[8];
#pragma unroll
  for (int i = 0; i < 8; ++i) acc[i] = 0.f;
  for (int s2 = 0; s2 < nseg; ++s2) {
    int4 v = *(const int4*)(po + (size_t)(sid0 + s2) * 2048 + q * 128 + h0);
    const unsigned int* pu = (const unsigned int*)&v;
    const float as = w[s2];
#pragma unroll
    for (int cidx = 0; cidx < 4; ++cidx) {
      unsigned int u = pu[cidx];
      acc[cidx * 2 + 0] += as * b2f((unsigned short)(u & 0xFFFF));
      acc[cidx * 2 + 1] += as * b2f((unsigned short)(u >> 16));
    }
  }
  const float inv = 1.0f / lsum;
  float* o = out + ((size_t)(b * T_ + j2 * 16 + q)) * H_ + h0;
  float4 v0 = make_float4(acc[0] * inv, acc[1] * inv, acc[2] * inv, acc[3] * inv);
  float4 v1 = make_float4(acc[4] * inv, acc[5] * inv, acc[6] * inv, acc[7] * inv);
  *(float4*)(o + 0) = v0;
  *(float4*)(o + 4) = v1;
}

// ---------------------------------------------------------------------------
extern "C" void kernel_launch(void* const* d_in, const int* in_sizes, int n_in,
                              void* d_out, int out_size, void* d_ws, size_t ws_size,
                              hipStream_t stream) {
  const float* x  = (const float*)d_in[0];
  const float* Wq = (const float*)d_in[1];
  const float* Wk = (const float*)d_in[2];
  const float* Wv = (const float*)d_in[3];
  float* out = (float*)d_out;

  char* ws = (char*)d_ws;
  short* qb  = (short*)(ws);                // 4 MB    q  bf16 [BT][128]
  short* kb  = (short*)(ws + 4194304);      // 4 MB    k  bf16 [BT][128]
  short* vtb = (short*)(ws + 8388608);      // 4 MB    v^T bf16 [B][128][T]
  short* Wt  = (short*)(ws + 12582912);     // 0.75 MB W^T bf16 [3][128][1024]
  short* po  = (short*)(ws + 14680064);     // 10.5 MB partial O bf16 (2560 x 4 KB)
  float* pm  = (float*)(ws + 25165824);     // 160 KB  partial m (log2 domain)
  float* pl  = (float*)(ws + 25329664);     // 160 KB  partial l

  wcvt_kernel<<<dim3(D_ / 64, 3), 256, 0, stream>>>(Wq, Wk, Wv, Wt);
  proj_kernel<<<dim3(BT / 64, 3), 256, 0, stream>>>(x, Wt, qb, kb, vtb);
  attn_part<<<dim3(2560), 64, 0, stream>>>(qb, kb, vtb, po, pm, pl);
  attn_reduce<<<dim3(8 * 128), 256, 0, stream>>>(po, pm, pl, out);
}

// Round 15
// 194.582 us; speedup vs baseline: 1.0331x; 1.0331x over previous
//
#include <hip/hip_runtime.h>
#include <math.h>

#define B_ 8
#define T_ 2048
#define D_ 1024
#define H_ 128
#define BT (B_ * T_)

typedef short bf16x8 __attribute__((ext_vector_type(8)));
typedef float f32x4 __attribute__((ext_vector_type(4)));

static constexpr float SCALE = 0.08838834764831845f;  // 1/sqrt(128)

__device__ inline unsigned short f2b(float f) {
  unsigned int u = __float_as_uint(f);
  u += 0x7FFF + ((u >> 16) & 1);  // RNE
  return (unsigned short)(u >> 16);
}
__device__ inline unsigned int pk2(float a, float b) {
  return (unsigned int)f2b(a) | ((unsigned int)f2b(b) << 16);
}

// global (AS1) -> LDS (AS3) direct 16B copy; dest = wave-uniform base + lane*16
__device__ __forceinline__ void gll16(const void* g, void* l) {
  __builtin_amdgcn_global_load_lds(
      (const __attribute__((address_space(1))) void*)g,
      (__attribute__((address_space(3))) void*)l, 16, 0, 0);
}

// ---------------------------------------------------------------------------
// Setup: W[d][h] fp32 -> Wt[sel][h][d] bf16 through LDS, coalesced stores.
// ---------------------------------------------------------------------------
__global__ __launch_bounds__(256) void wcvt_kernel(
    const float* __restrict__ Wq, const float* __restrict__ Wk,
    const float* __restrict__ Wv, short* __restrict__ Wt) {
  __shared__ short Wls[128 * 72];  // [h][d] bf16, pitch 72
  const int sel = blockIdx.y;
  const float* W = sel == 0 ? Wq : (sel == 1 ? Wk : Wv);
  const int d0 = blockIdx.x * 64;
  const int tid = threadIdx.x;
#pragma unroll
  for (int i = 0; i < 8; ++i) {
    int slot = tid + i * 256;         // 2048 float4 slots: 64 d x 32 h-groups
    int r = slot >> 5, hg = slot & 31;
    float4 w = *(const float4*)(W + (size_t)(d0 + r) * H_ + hg * 4);
    Wls[(hg * 4 + 0) * 72 + r] = (short)f2b(w.x);
    Wls[(hg * 4 + 1) * 72 + r] = (short)f2b(w.y);
    Wls[(hg * 4 + 2) * 72 + r] = (short)f2b(w.z);
    Wls[(hg * 4 + 3) * 72 + r] = (short)f2b(w.w);
  }
  __syncthreads();
  short* dst = Wt + (size_t)sel * D_ * H_;
#pragma unroll
  for (int i = 0; i < 4; ++i) {
    int slot = tid + i * 256;         // 1024 int4 slots: 128 h x 8 d-groups
    int h = slot >> 3, g = slot & 7;
    *(int4*)(dst + (size_t)h * D_ + d0 + g * 8) = *(int4*)&Wls[h * 72 + g * 8];
  }
}

// ---------------------------------------------------------------------------
// Proj v4 FUSED: one block = 32 x-rows x ALL 384 output cols (q|k|v), so x is
// read ONCE (was 3x = 192 MB -> 64 MB). W fragments load directly from global:
// 0.75 MB Wt is permanently L2-resident per XCD (r14-validated mechanism).
// Grid 512 = exactly 2 blocks/CU. X staged in LDS (dbuf, issue-early/pack-
// late); wave tile 32 rows x 96 cols (acc 2x6). Epilogue: q|k row-major +
// v transposed via LDS repack, int4 stores.
// ---------------------------------------------------------------------------
__global__ __launch_bounds__(256) void proj_kernel(
    const float* __restrict__ x, const short* __restrict__ Wt,
    short* __restrict__ qb, short* __restrict__ kb, short* __restrict__ vtb) {
  __shared__ alignas(16) char smem[27648];
  short* Xs0 = (short*)smem;            // [32][64] bf16 swizzled (4 KB)
  short* Xs1 = (short*)(smem + 4096);

  const int tid = threadIdx.x;
  const int wave = tid >> 6, lane = tid & 63;
  const int ln = lane & 15, quad = lane >> 4;
  const int row0 = blockIdx.x * 32;

  f32x4 acc[2][6];
#pragma unroll
  for (int mi = 0; mi < 2; ++mi)
#pragma unroll
    for (int ni = 0; ni < 6; ++ni) acc[mi][ni] = (f32x4){0.f, 0.f, 0.f, 0.f};

  // W row pointers for this wave's 6 col-tiles (sel folded into address)
  const short* wp[6];
#pragma unroll
  for (int ni = 0; ni < 6; ++ni) {
    int ng = wave * 96 + ni * 16 + ln;          // global col 0..383
    wp[ni] = Wt + (size_t)(ng >> 7) * (D_ * H_) + (size_t)(ng & 127) * D_;
  }

  auto packX = [&](int bf, const float4* xr) {
    short* Xs = bf ? Xs1 : Xs0;
#pragma unroll
    for (int i = 0; i < 2; ++i) {
      int fid = tid + i * 256;         // 512 float4 slots: 32 rows x 16
      int r = fid >> 4, g4 = fid & 15;
      int g = g4 >> 1, half = g4 & 1;
      unsigned int* p = (unsigned int*)&Xs[r * 64 + ((g ^ (r & 7)) * 8) + half * 4];
      p[0] = pk2(xr[i].x, xr[i].y);
      p[1] = pk2(xr[i].z, xr[i].w);
    }
  };

  {  // prologue: stage 0
    float4 xr[2];
#pragma unroll
    for (int i = 0; i < 2; ++i) {
      int fid = tid + i * 256;
      int r = fid >> 4, g4 = fid & 15;
      xr[i] = *(const float4*)(x + (size_t)(row0 + r) * D_ + g4 * 4);
    }
    packX(0, xr);
  }

  for (int s = 0; s < 16; ++s) {
    const int k0 = s * 64;
    __syncthreads();  // X(s) staged; X(s^1) free
    float4 xr[2];
    const bool pre = (s < 15);
    if (pre) {
      const int k0n = k0 + 64;
#pragma unroll
      for (int i = 0; i < 2; ++i) {   // issue early...
        int fid = tid + i * 256;
        int r = fid >> 4, g4 = fid & 15;
        xr[i] = *(const float4*)(x + (size_t)(row0 + r) * D_ + k0n + g4 * 4);
      }
    }
    // W frags direct from global (L2-resident): 12 independent b128 loads
    bf16x8 wf[2][6];
#pragma unroll
    for (int kk = 0; kk < 2; ++kk)
#pragma unroll
      for (int ni = 0; ni < 6; ++ni)
        wf[kk][ni] = *(const bf16x8*)(wp[ni] + k0 + kk * 32 + quad * 8);

    const short* Xs = (s & 1) ? Xs1 : Xs0;
#pragma unroll
    for (int kk = 0; kk < 2; ++kk) {
      bf16x8 a[2];
#pragma unroll
      for (int mi = 0; mi < 2; ++mi) {
        int r = mi * 16 + ln;
        a[mi] = *(bf16x8*)&Xs[r * 64 + (((kk * 4 + quad) ^ (r & 7)) * 8)];
      }
#pragma unroll
      for (int ni = 0; ni < 6; ++ni)
#pragma unroll
        for (int mi = 0; mi < 2; ++mi)
          acc[mi][ni] = __builtin_amdgcn_mfma_f32_16x16x32_bf16(a[mi], wf[kk][ni], acc[mi][ni], 0, 0, 0);
    }
    if (pre) packX((s + 1) & 1, xr);  // ...use late (after compute)
  }

  __syncthreads();  // X dead; reuse smem for epilogue
  short* CsQK = (short*)smem;            // [32][264] = 16896 B (q|k cols 0..255)
  short* CsV  = (short*)(smem + 16896);  // [128][40] = 10240 B (v transposed)
#pragma unroll
  for (int mi = 0; mi < 2; ++mi)
#pragma unroll
    for (int ni = 0; ni < 6; ++ni) {
      int ng = wave * 96 + ni * 16 + ln;
#pragma unroll
      for (int rr = 0; rr < 4; ++rr) {
        int row = mi * 16 + quad * 4 + rr;
        float v = acc[mi][ni][rr];
        if (ng < 256) CsQK[row * 264 + ng] = (short)f2b(v);
        else          CsV[(ng - 256) * 40 + row] = (short)f2b(v);
      }
    }
  __syncthreads();
  // q|k: 1024 int4 slots (32 rows x 32 col-groups)
#pragma unroll
  for (int i = 0; i < 4; ++i) {
    int s2 = tid + i * 256;
    int row = s2 >> 5, g = s2 & 31;
    int4 v = *(int4*)&CsQK[row * 264 + g * 8];
    if (g < 16) *(int4*)(qb + (size_t)(row0 + row) * H_ + g * 8) = v;
    else        *(int4*)(kb + (size_t)(row0 + row) * H_ + (g - 16) * 8) = v;
  }
  // v: 512 int4 slots (128 h x 4 t-groups)
  const int b = row0 >> 11, t0 = row0 & 2047;
#pragma unroll
  for (int i = 0; i < 2; ++i) {
    int s2 = tid + i * 256;
    int h = s2 >> 2, g = s2 & 3;
    *(int4*)(vtb + (size_t)(b * H_ + h) * T_ + t0 + g * 8) = *(int4*)&CsV[h * 40 + g * 8];
  }
}

// ---------------------------------------------------------------------------
// Attention part 1: key-split flash attention partials (ROUND-11 VERBATIM —
// best measured config: 41.6 us, MfmaUtil 7.5). 256 thr, 64 q/block (wave-
// decoupled 16 q/wave), segments <=8 chunks, 640 blocks heavy-first, K/V
// double-buffered gll, one barrier per chunk.
// ---------------------------------------------------------------------------
__global__ __launch_bounds__(256) void attn_part(
    const short* __restrict__ qb, const short* __restrict__ kb,
    const short* __restrict__ vtb, float* __restrict__ po,
    float* __restrict__ pm, float* __restrict__ pl) {
  __shared__ alignas(16) char smem[74240];
  short* Ks0 = (short*)smem;               // [64][128] bf16 swizzled
  short* Ks1 = (short*)(smem + 16384);
  short* Vt0 = (short*)(smem + 32768);     // [128][64] bf16 swizzled
  short* Vt1 = (short*)(smem + 49152);
  short* Pt  = (short*)(smem + 65536);     // 4 waves x [16][68] bf16

  const int tid = threadIdx.x;
  const int wv = tid >> 6, lane = tid & 63;
  const int ln = lane & 15, quad = lane >> 4;
  const int b = blockIdx.x / 80;
  const int rr = 79 - (blockIdx.x % 80);   // heavy segments first
  const int g = (rr >= 48) ? 3 : (rr >= 24) ? 2 : (rr >= 8) ? 1 : 0;
  const int local = rr - 4 * g * (g + 1);
  const int j = 8 * g + local / (g + 1);
  const int s = local - (local / (g + 1)) * (g + 1);
  const int sid = b * 80 + rr;             // partial storage slot
  const int q0 = j * 64;
  const int nchunks = min(8, j + 1 - 8 * s);

  short* myP = Pt + wv * (16 * 68);

  bf16x8 qfr[4];  // this wave's 16 queries, B-operand layout
#pragma unroll
  for (int kk = 0; kk < 4; ++kk)
    qfr[kk] = *(const bf16x8*)(qb + (size_t)(b * T_ + q0 + wv * 16 + ln) * H_ +
                               kk * 32 + quad * 8);

  f32x4 oacc[8];  // O^T: h = ht*16+quad*4+r, q = ln
#pragma unroll
  for (int ht = 0; ht < 8; ++ht) oacc[ht] = (f32x4){0.f, 0.f, 0.f, 0.f};

  float m_run = -INFINITY, l_run = 0.f;
  const int qglob = q0 + wv * 16 + ln;

  auto stageK = [&](short* dst, int s0) {
#pragma unroll
    for (int jj = 0; jj < 4; ++jj) {
      const int rb = wv * 16 + jj * 4;       // 16 rows per wave
      const int r = rb + (lane >> 4);
      const int gp = (lane & 15) ^ (r & 7);
      gll16(kb + (size_t)(b * T_ + s0 + r) * H_ + gp * 8, (char*)dst + rb * 256);
    }
  };
  auto stageV = [&](short* dst, int s0) {
#pragma unroll
    for (int jj = 0; jj < 4; ++jj) {
      const int hb = wv * 32 + jj * 8;       // 32 rows per wave
      const int h = hb + (lane >> 3);
      const int gp = (lane & 7) ^ (h & 7);
      gll16(vtb + (size_t)(b * H_ + h) * T_ + s0 + gp * 8, (char*)dst + hb * 128);
    }
  };

  stageK(Ks0, 8 * s * 64);  // prologue: first chunk of this segment
  stageV(Vt0, 8 * s * 64);

  for (int ch = 0; ch < nchunks; ++ch) {
    const int s0 = (8 * s + ch) * 64;
    const int cur = ch & 1;
    __syncthreads();  // drains gll for buf[cur]; other buffer free to restage
    if (ch + 1 < nchunks) {
      stageK(cur ? Ks0 : Ks1, s0 + 64);
      stageV(cur ? Vt0 : Vt1, s0 + 64);
    }
    const short* Kc = cur ? Ks1 : Ks0;
    const short* Vc = cur ? Vt1 : Vt0;

    // S^T = K * Q^T : 4 key-tiles x 4 kk = 16 MFMAs (per wave, its 16 q)
    f32x4 sacc[4];
#pragma unroll
    for (int t = 0; t < 4; ++t) sacc[t] = (f32x4){0.f, 0.f, 0.f, 0.f};
#pragma unroll
    for (int kk = 0; kk < 4; ++kk) {
#pragma unroll
      for (int t = 0; t < 4; ++t) {
        const int krow = t * 16 + ln;
        bf16x8 kf = *(bf16x8*)&Kc[krow * 128 + (((kk * 4 + quad) ^ (ln & 7)) * 8)];
        sacc[t] = __builtin_amdgcn_mfma_f32_16x16x32_bf16(kf, qfr[kk], sacc[t], 0, 0, 0);
      }
    }

    // wave-local online softmax over keys
    float sv[4][4];
    float mc = -INFINITY;
#pragma unroll
    for (int t = 0; t < 4; ++t)
#pragma unroll
      for (int r = 0; r < 4; ++r) {
        const int key = s0 + t * 16 + quad * 4 + r;
        float sc = sacc[t][r] * SCALE;
        sv[t][r] = (key <= qglob) ? sc : -INFINITY;
        mc = fmaxf(mc, sv[t][r]);
      }
    mc = fmaxf(mc, __shfl_xor(mc, 16));
    mc = fmaxf(mc, __shfl_xor(mc, 32));
    const float mnew = fmaxf(m_run, mc);
    const float alpha = __expf(m_run - mnew);
    float lc = 0.f;
    float p[4][4];
#pragma unroll
    for (int t = 0; t < 4; ++t)
#pragma unroll
      for (int r = 0; r < 4; ++r) {
        p[t][r] = __expf(sv[t][r] - mnew);
        lc += p[t][r];
      }
    lc += __shfl_xor(lc, 16);
    lc += __shfl_xor(lc, 32);
    l_run = l_run * alpha + lc;
    m_run = mnew;

    // P^T -> wave-private LDS scratch (lgkm-ordered; no barrier needed)
#pragma unroll
    for (int t = 0; t < 4; ++t) {
      *(unsigned int*)&myP[ln * 68 + t * 16 + quad * 4 + 0] = pk2(p[t][0], p[t][1]);
      *(unsigned int*)&myP[ln * 68 + t * 16 + quad * 4 + 2] = pk2(p[t][2], p[t][3]);
    }
#pragma unroll
    for (int ht = 0; ht < 8; ++ht)
#pragma unroll
      for (int r = 0; r < 4; ++r) oacc[ht][r] *= alpha;

    // O^T += V^T * P^T : 8 h-tiles x 2 kk = 16 MFMAs
#pragma unroll
    for (int kk2 = 0; kk2 < 2; ++kk2) {
      bf16x8 pf = *(bf16x8*)&myP[ln * 68 + kk2 * 32 + quad * 8];
#pragma unroll
      for (int ht = 0; ht < 8; ++ht) {
        const int hrow = ht * 16 + ln;
        bf16x8 vf = *(bf16x8*)&Vc[hrow * 64 + (((kk2 * 4 + quad) ^ (ln & 7)) * 8)];
        oacc[ht] = __builtin_amdgcn_mfma_f32_16x16x32_bf16(vf, pf, oacc[ht], 0, 0, 0);
      }
    }
  }

  // write partial: m, l per query; un-normalized O via LDS transpose
  if (quad == 0) {
    pm[(size_t)sid * 64 + wv * 16 + ln] = m_run;
    pl[(size_t)sid * 64 + wv * 16 + ln] = l_run;
  }
  __syncthreads();  // Ks/Vt dead; reuse for Ot
  float* Ot = (float*)smem;  // [64][132] f32 = 33.8 KB
#pragma unroll
  for (int ht = 0; ht < 8; ++ht)
    *(f32x4*)&Ot[(wv * 16 + ln) * 132 + ht * 16 + quad * 4] = oacc[ht];
  __syncthreads();
  float* dst = po + (size_t)sid * 8192;
#pragma unroll
  for (int i = 0; i < 8; ++i) {
    int slot2 = tid + i * 256;            // 2048 float4 slots: 64 q x 32
    int r2 = slot2 >> 5, c2 = slot2 & 31;
    *(f32x4*)(dst + r2 * 128 + c2 * 4) = *(f32x4*)&Ot[r2 * 132 + c2 * 4];
  }
}

// ---------------------------------------------------------------------------
// Attention part 2: combine <=4 partials per (b, 64q-tile) with max-rescale
// (ROUND-11 VERBATIM). 256 blocks x 256 thr.
// ---------------------------------------------------------------------------
__global__ __launch_bounds__(256) void attn_reduce(
    const float* __restrict__ po, const float* __restrict__ pm,
    const float* __restrict__ pl, float* __restrict__ out) {
  const int b = blockIdx.x >> 5;
  const int j = blockIdx.x & 31;
  const int g = j >> 3;
  const int nseg = g + 1;
  const int sid0 = b * 80 + 4 * g * (g + 1) + (j - 8 * g) * nseg;
  const int tid = threadIdx.x;
  const int q = tid >> 2, hq = tid & 3;

  float m[4], l[4], a[4];
  float M = -INFINITY;
  for (int s2 = 0; s2 < nseg; ++s2) {
    m[s2] = pm[(size_t)(sid0 + s2) * 64 + q];
    l[s2] = pl[(size_t)(sid0 + s2) * 64 + q];
    M = fmaxf(M, m[s2]);
  }
  float lsum = 0.f;
  for (int s2 = 0; s2 < nseg; ++s2) {
    a[s2] = __expf(m[s2] - M);
    lsum += a[s2] * l[s2];
  }
  f32x4 acc[8];
#pragma unroll
  for (int i = 0; i < 8; ++i) acc[i] = (f32x4){0.f, 0.f, 0.f, 0.f};
  for (int s2 = 0; s2 < nseg; ++s2) {
    const float* src = po + (size_t)(sid0 + s2) * 8192 + q * 128 + hq * 32;
    const float as = a[s2];
#pragma unroll
    for (int i = 0; i < 8; ++i) {
      f32x4 v = *(const f32x4*)(src + i * 4);
#pragma unroll
      for (int c = 0; c < 4; ++c) acc[i][c] += as * v[c];
    }
  }
  const float inv = 1.0f / lsum;
  float* o = out + ((size_t)(b * T_ + j * 64 + q)) * H_ + hq * 32;
#pragma unroll
  for (int i = 0; i < 8; ++i) {
    f32x4 v;
#pragma unroll
    for (int c = 0; c < 4; ++c) v[c] = acc[i][c] * inv;
    *(f32x4*)(o + i * 4) = v;
  }
}

// ---------------------------------------------------------------------------
extern "C" void kernel_launch(void* const* d_in, const int* in_sizes, int n_in,
                              void* d_out, int out_size, void* d_ws, size_t ws_size,
                              hipStream_t stream) {
  const float* x  = (const float*)d_in[0];
  const float* Wq = (const float*)d_in[1];
  const float* Wk = (const float*)d_in[2];
  const float* Wv = (const float*)d_in[3];
  float* out = (float*)d_out;

  char* ws = (char*)d_ws;
  short* qb  = (short*)(ws);                // 4 MB   q  bf16 [BT][128]
  short* kb  = (short*)(ws + 4194304);      // 4 MB   k  bf16 [BT][128]
  short* vtb = (short*)(ws + 8388608);      // 4 MB   v^T bf16 [B][128][T]
  short* Wt  = (short*)(ws + 12582912);     // 0.75 MB W^T bf16 [3][128][1024]
  float* po  = (float*)(ws + 14680064);     // 20 MB  partial O (640 x 32 KB)
  float* pm  = (float*)(ws + 35651584);     // 160 KB partial m
  float* pl  = (float*)(ws + 35915776);     // 160 KB partial l

  wcvt_kernel<<<dim3(D_ / 64, 3), 256, 0, stream>>>(Wq, Wk, Wv, Wt);
  proj_kernel<<<dim3(BT / 32), 256, 0, stream>>>(x, Wt, qb, kb, vtb);
  attn_part<<<dim3(8 * 80), 256, 0, stream>>>(qb, kb, vtb, po, pm, pl);
  attn_reduce<<<dim3(8 * 32), 256, 0, stream>>>(po, pm, pl, out);
}